// Round 3
// baseline (449.144 us; speedup 1.0000x reference)
//
#include <hip/hip_runtime.h>

#define BB 4
#define SS 4096
#define DD 64
#define QB 64           // queries per block: 2 qgroups x 32
#define NKI 128         // keys staged per iteration
#define NIT (SS / NKI)  // 32
#define IMGB 49152      // per-tile image: Vhi 16K + Vlo 16K + VTr 16K
// image layout (per tile, XOR-swizzled in 16B chunks so ds_read_b128 is conflict-free):
//   Vhi[k][d]  @ 0     : chunk (k, d>>3)  stored at k*128 + ((d>>3)^(k&7))*16
//   Vlo[k][d]  @ 16384 : same scheme (f16x2 residual, Sterbenz-exact)
//   VTr[d][k]  @ 32768 : chunk (d, k>>3)  stored at d*256 + ((k>>3)^(d&7))*16

typedef _Float16 h16;
typedef h16 half2_t __attribute__((ext_vector_type(2)));
typedef h16 half8_t __attribute__((ext_vector_type(8)));
typedef float f32x4 __attribute__((ext_vector_type(4)));
typedef float f32x16 __attribute__((ext_vector_type(16)));
typedef unsigned u32x4v __attribute__((ext_vector_type(4)));

typedef __attribute__((address_space(3))) uint32_t lds_u32;
typedef const __attribute__((address_space(1))) uint32_t gl_u32;

#define Z16 ((f32x16){0.f,0.f,0.f,0.f,0.f,0.f,0.f,0.f,0.f,0.f,0.f,0.f,0.f,0.f,0.f,0.f})

template <int NC>
__device__ __forceinline__ void stage_img(const char* g, char* l, int t) {
#pragma unroll
    for (int i = 0; i < NC; ++i) {
        const int off = (i * 512 + t) * 16;
        __builtin_amdgcn_global_load_lds((gl_u32*)(g + off), (lds_u32*)(l + off), 16, 0, 0);
    }
}

__device__ __forceinline__ unsigned pkh(float a, float b) {
    half2_t x = {(h16)a, (h16)b};          // RNE casts, same values as before
    return __builtin_bit_cast(unsigned, x);
}

// Exchange so that (wl,wh) become PV B-frag words (low,high) for this lane's half.
// Direction-agnostic: uses shfl_xor(32) + per-lane select instead of permlane.
__device__ __forceinline__ void xpair(unsigned& wl, unsigned& wh, int h) {
    unsigned xl = (unsigned)__shfl_xor((int)wl, 32);
    unsigned xh = (unsigned)__shfl_xor((int)wh, 32);
    unsigned nl = h ? xh : wl;
    unsigned nh = h ? wh : xl;
    wl = nl; wh = nh;
}

// ---------------- prep: f32 V -> swizzled f16x2-split tile images ----------------
__global__ __launch_bounds__(512) void prep_v(const float* __restrict__ V,
                                              char* __restrict__ W) {
    __shared__ h16 VT[64][128];
    const int t  = threadIdx.x;
    const int it = blockIdx.x;
    const int b  = blockIdx.y;
    const int k  = t >> 2;        // key 0..127
    const int dc = t & 3;         // d-chunk of 16
    char* img = W + ((size_t)b * NIT + it) * IMGB;
    const float* src = V + ((size_t)b * SS + (size_t)it * NKI + k) * DD + dc * 16;
#pragma unroll
    for (int o = 0; o < 2; ++o) {
        f32x4 a = *(const f32x4*)(src + o * 8);
        f32x4 c = *(const f32x4*)(src + o * 8 + 4);
        half8_t hi, lo;
#pragma unroll
        for (int j = 0; j < 4; ++j) {
            float x = a[j]; h16 hh = (h16)x;
            hi[j] = hh; lo[j] = (h16)(x - (float)hh);
            float y = c[j]; h16 gg = (h16)y;
            hi[j + 4] = gg; lo[j + 4] = (h16)(y - (float)gg);
        }
        const int cc = (dc * 2 + o) ^ (k & 7);
        *(half8_t*)(img + (size_t)k * 128 + cc * 16) = hi;
        *(half8_t*)(img + 16384 + (size_t)k * 128 + cc * 16) = lo;
        const int d0 = dc * 16 + o * 8;
#pragma unroll
        for (int j = 0; j < 8; ++j) VT[d0 + j][k] = hi[j];
    }
    __syncthreads();
#pragma unroll
    for (int j = 0; j < 2; ++j) {
        const int ci = j * 512 + t;      // 1024 chunks of VTr
        const int d  = ci >> 4;
        const int cc = ci & 15;
        const int k0 = (cc ^ (d & 7)) * 8;
        half8_t v = *(const half8_t*)&VT[d][k0];
        *(half8_t*)(img + 32768 + (size_t)d * 256 + cc * 16) = v;
    }
}

// S^T = V*Q^T for one 32-key slot x 32 queries; split accumulators break the MFMA chain.
__device__ __forceinline__ f32x16 scores32(const char* buf, int kq, int h, int kr, int x7,
                                           const half8_t* qh, const half8_t* ql) {
    const char* Vh = buf + (size_t)(kq * 32 + kr) * 128;
    const char* Vl = Vh + 16384;
    f32x16 sa = Z16, sb = Z16;
#pragma unroll
    for (int s = 0; s < 4; ++s) {
        const int cc = ((s * 2 + h) ^ x7) << 4;
        half8_t ah = *(const half8_t*)(Vh + cc);
        half8_t al = *(const half8_t*)(Vl + cc);
        if (s & 1) {
            sb = __builtin_amdgcn_mfma_f32_32x32x16_f16(ah, qh[s], sb, 0, 0, 0);
            sb = __builtin_amdgcn_mfma_f32_32x32x16_f16(ah, ql[s], sb, 0, 0, 0);
            sb = __builtin_amdgcn_mfma_f32_32x32x16_f16(al, qh[s], sb, 0, 0, 0);
        } else {
            sa = __builtin_amdgcn_mfma_f32_32x32x16_f16(ah, qh[s], sa, 0, 0, 0);
            sa = __builtin_amdgcn_mfma_f32_32x32x16_f16(ah, ql[s], sa, 0, 0, 0);
            sa = __builtin_amdgcn_mfma_f32_32x32x16_f16(al, qh[s], sa, 0, 0, 0);
        }
    }
    return sa + sb;
}

__device__ __forceinline__ void p1_step(const char* buf, int kq, int h, int kr, int x7,
                                        const half8_t* qh, const half8_t* ql,
                                        float& mrun, float& lrun, f32x16& oc0, f32x16& oc1) {
    f32x16 sc = scores32(buf, kq, h, kr, x7, qh, ql);

    float tmax = sc[0];
#pragma unroll
    for (int i = 1; i < 16; ++i) tmax = fmaxf(tmax, sc[i]);
    tmax = fmaxf(tmax, __shfl_xor(tmax, 32));
    const float mn = fmaxf(mrun, tmax);
    float p[16], ps = 0.f;
#pragma unroll
    for (int i = 0; i < 16; ++i) { p[i] = __expf(sc[i] - mn); ps += p[i]; }
    ps += __shfl_xor(ps, 32);
    const bool still = __all(tmax <= mrun);     // alpha == 1 exactly -> skip rescale
    const float alpha = still ? 1.f : __expf(mrun - mn);
    lrun = lrun * alpha + ps;
    mrun = mn;
    if (!still) { oc0 *= alpha; oc1 *= alpha; }

    // pack P to f16 words; in-register half-exchange builds both PV B-frags
    unsigned w0 = pkh(p[0], p[1]),   w1 = pkh(p[2], p[3]);
    unsigned w2 = pkh(p[4], p[5]),   w3 = pkh(p[6], p[7]);
    unsigned w4 = pkh(p[8], p[9]),   w5 = pkh(p[10], p[11]);
    unsigned w6 = pkh(p[12], p[13]), w7 = pkh(p[14], p[15]);
    xpair(w0, w2, h); xpair(w1, w3, h); xpair(w4, w6, h); xpair(w5, w7, h);
    half8_t pb0 = __builtin_bit_cast(half8_t, (u32x4v){w0, w1, w2, w3});
    half8_t pb1 = __builtin_bit_cast(half8_t, (u32x4v){w4, w5, w6, w7});

    // O^T += V^T * P^T over this 32-key slot (hi-only V, as before)
    const char* VT = buf + 32768 + (size_t)kr * 256;
#pragma unroll
    for (int ks = 0; ks < 2; ++ks) {
        const half8_t bp = ks ? pb1 : pb0;
        const int c0 = ((kq * 4 + ks * 2 + h) ^ x7) << 4;
        half8_t av0 = *(const half8_t*)(VT + c0);
        half8_t av1 = *(const half8_t*)(VT + 32 * 256 + c0);
        oc0 = __builtin_amdgcn_mfma_f32_32x32x16_f16(av0, bp, oc0, 0, 0, 0);
        oc1 = __builtin_amdgcn_mfma_f32_32x32x16_f16(av1, bp, oc1, 0, 0, 0);
    }
}

__device__ __forceinline__ void p2_step(const char* buf, int it, int kq, int h, int kr, int x7,
                                        const half8_t* qh, const half8_t* ql,
                                        float moff, float* arow) {
    f32x16 sc = scores32(buf, kq, h, kr, x7, qh, ql);
    const int colb = it * NKI + kq * 32 + h * 4;
#pragma unroll
    for (int g = 0; g < 4; ++g) {
        f32x4 wv;
#pragma unroll
        for (int m = 0; m < 4; ++m) wv[m] = __expf(sc[g * 4 + m] - moff);
        __builtin_nontemporal_store(wv, (f32x4*)&arow[colb + g * 8]);
    }
}

__global__ __launch_bounds__(512, 2) void attn_fused(const float* __restrict__ Q,
                                                     const char* __restrict__ W,
                                                     float* __restrict__ ctx,
                                                     float* __restrict__ attn) {
    __shared__ __align__(16) char B0[IMGB];
    __shared__ __align__(16) char B1[IMGB];
    const int t    = threadIdx.x;
    const int wid  = t >> 6;
    const int lane = t & 63;
    const int kr   = lane & 31;    // A-row / C-col index
    const int h    = lane >> 5;    // half 0/1
    const int x7   = kr & 7;
    const int qgrp = wid & 1;
    const int kq   = wid >> 1;     // key quarter 0..3 (split-K=4)
    const int bid  = blockIdx.x;
    const int b    = bid & 3;      // batch pinned per XCD class (bid%8 -> one batch)
    const int qg   = (bid >> 2) * QB + qgrp * 32 + kr;   // global query row

    const char* Wb    = W + (size_t)b * NIT * IMGB;
    const float* Qrow = Q + ((size_t)b * SS + qg) * DD;

    // Q fragments f16x2: lane holds Q[q=lane&31][d = s*16 + h*8 + j]
    half8_t qh[4], ql[4];
#pragma unroll
    for (int s = 0; s < 4; ++s) {
        f32x4 a = *(const f32x4*)(Qrow + s * 16 + h * 8);
        f32x4 c = *(const f32x4*)(Qrow + s * 16 + h * 8 + 4);
#pragma unroll
        for (int j = 0; j < 4; ++j) {
            float x = a[j]; h16 hh = (h16)x;
            qh[s][j] = hh; ql[s][j] = (h16)(x - (float)hh);
            float y = c[j]; h16 gg = (h16)y;
            qh[s][j + 4] = gg; ql[s][j + 4] = (h16)(y - (float)gg);
        }
    }

    float mrun = -1e30f, lrun = 0.f;
    f32x16 oc0 = Z16, oc1 = Z16;

    // ---------------- Phase 1: double-buffered, 1 barrier/iter ----------------
    stage_img<6>(Wb, B0, t);
    __syncthreads();
#pragma unroll 1
    for (int it = 0; it < NIT; it += 2) {
        stage_img<6>(Wb + (size_t)(it + 1) * IMGB, B1, t);      // issue-early
        p1_step(B0, kq, h, kr, x7, qh, ql, mrun, lrun, oc0, oc1);
        __syncthreads();
        if (it + 2 < NIT) stage_img<6>(Wb + (size_t)(it + 2) * IMGB, B0, t);
        p1_step(B1, kq, h, kr, x7, qh, ql, mrun, lrun, oc0, oc1);
        __syncthreads();
    }

    // ---------------- Merge 4 split-K partners (two passes, fixed order) ------
    float efac[4], mf, lf;
    {
        float* buf  = (float*)B0;
        float* mine = buf + t * 18;
        mine[0] = mrun; mine[1] = lrun;
#pragma unroll
        for (int i = 0; i < 16; ++i) mine[2 + i] = oc0[i];
        __syncthreads();
        mf = -1e30f;
#pragma unroll
        for (int k2 = 0; k2 < 4; ++k2)
            mf = fmaxf(mf, buf[((qgrp + 2 * k2) * 64 + lane) * 18]);
        lf = 0.f;
        f32x16 n0 = Z16;
#pragma unroll
        for (int k2 = 0; k2 < 4; ++k2) {
            const float* po = buf + ((qgrp + 2 * k2) * 64 + lane) * 18;
            float e = __expf(po[0] - mf);
            efac[k2] = e;
            lf += po[1] * e;
#pragma unroll
            for (int i = 0; i < 16; ++i) n0[i] += po[2 + i] * e;
        }
        __syncthreads();
        float* buf1  = (float*)B1;
        float* mine1 = buf1 + t * 16;
#pragma unroll
        for (int i = 0; i < 16; ++i) mine1[i] = oc1[i];
        __syncthreads();
        f32x16 n1 = Z16;
#pragma unroll
        for (int k2 = 0; k2 < 4; ++k2) {
            const float* po = buf1 + ((qgrp + 2 * k2) * 64 + lane) * 16;
#pragma unroll
            for (int i = 0; i < 16; ++i) n1[i] += po[i] * efac[k2];
        }
        oc0 = n0; oc1 = n1;
        mrun = mf; lrun = lf;
    }
    __syncthreads();                 // B0/B1 free again

    stage_img<4>(Wb, B0, t);         // phase-2 prologue (Vhi+Vlo prefix only)

    const float invl = 1.f / lrun;
    if (kq == 0) {                   // ctx write: lane holds d=(m)+8g+4h(+32*tile), q=kr
        float* crow = ctx + ((size_t)b * SS + qg) * DD;
#pragma unroll
        for (int g = 0; g < 4; ++g) {
            f32x4 c0, c1;
#pragma unroll
            for (int m = 0; m < 4; ++m) { c0[m] = oc0[g * 4 + m] * invl; c1[m] = oc1[g * 4 + m] * invl; }
            *(f32x4*)&crow[g * 8 + h * 4] = c0;
            *(f32x4*)&crow[32 + g * 8 + h * 4] = c1;
        }
    }
    const float moff = mrun + __logf(lrun);   // exp(s-m)/l == exp(s-moff)
    float* arow = attn + ((size_t)b * SS + qg) * SS;
    __syncthreads();

    // ---------------- Phase 2: recompute scores, write normalized weights ----
#pragma unroll 1
    for (int it = 0; it < NIT; it += 2) {
        stage_img<4>(Wb + (size_t)(it + 1) * IMGB, B1, t);
        p2_step(B0, it, kq, h, kr, x7, qh, ql, moff, arow);
        __syncthreads();
        if (it + 2 < NIT) stage_img<4>(Wb + (size_t)(it + 2) * IMGB, B0, t);
        p2_step(B1, it + 1, kq, h, kr, x7, qh, ql, moff, arow);
        __syncthreads();
    }
}

extern "C" void kernel_launch(void* const* d_in, const int* in_sizes, int n_in,
                              void* d_out, int out_size, void* d_ws, size_t ws_size,
                              hipStream_t stream) {
    const float* Q = (const float*)d_in[0];
    const float* V = (const float*)d_in[1];
    float* ctx  = (float*)d_out;
    float* attn = (float*)d_out + (size_t)BB * SS * DD;
    char* W = (char*)d_ws;                       // BB*NIT*IMGB = 6.29 MiB
    prep_v<<<dim3(NIT, BB), 512, 0, stream>>>(V, W);
    attn_fused<<<dim3(BB * SS / QB), 512, 0, stream>>>(Q, W, ctx, attn);
}

// Round 4
// 372.657 us; speedup vs baseline: 1.2052x; 1.2052x over previous
//
#include <hip/hip_runtime.h>

#define BB 4
#define SS 4096
#define DD 64
#define NSLOT 128                       // 32-key slots per batch
#define SLOTB 12288                     // slot image: SCO 8K (4s x hi/lo x 64lanes x 16B) + PV 4K
#define IMGB ((size_t)NSLOT * SLOTB)    // 1.5 MiB per batch
#define KS 4                            // k-splits in the stats pass

typedef _Float16 h16;
typedef h16 half2_t __attribute__((ext_vector_type(2)));
typedef h16 half8_t __attribute__((ext_vector_type(8)));
typedef float f32x2 __attribute__((ext_vector_type(2)));
typedef float f32x4 __attribute__((ext_vector_type(4)));
typedef float f32x16 __attribute__((ext_vector_type(16)));
typedef unsigned u32x4v __attribute__((ext_vector_type(4)));

#define Z16 ((f32x16){0.f,0.f,0.f,0.f,0.f,0.f,0.f,0.f,0.f,0.f,0.f,0.f,0.f,0.f,0.f,0.f})

__device__ __forceinline__ unsigned pkh(float a, float b) {
    half2_t x = {(h16)a, (h16)b};
    return __builtin_bit_cast(unsigned, x);
}

// Exchange so (wl,wh) become the PV B-frag words for this lane's half.
__device__ __forceinline__ void xpair(unsigned& wl, unsigned& wh, int h) {
    unsigned xl = (unsigned)__shfl_xor((int)wl, 32);
    unsigned xh = (unsigned)__shfl_xor((int)wh, 32);
    unsigned nl = h ? xh : wl;
    unsigned nh = h ? wh : xl;
    wl = nl; wh = nh;
}

// ------------ prep: V -> fragment-major f16x2-split image (per 32-key slot) ------------
// SCO frag (s,hl): lane(kr,h) holds V[slot*32+kr][s*16+h*8 .. +7] hi (hl=0) / lo residual (hl=1)
// PV  frag (ks,o): lane(kr,h) holds V^T[o*32+kr][slot*32+ks*16+h*8 .. +7] (hi only)
__global__ __launch_bounds__(512) void prep_v(const float* __restrict__ V,
                                              char* __restrict__ W) {
    const int t    = threadIdx.x;
    const int slot = blockIdx.x;
    const int b    = blockIdx.y;
    char* img = W + (size_t)b * IMGB + (size_t)slot * SLOTB;
    const float* Vb = V + (size_t)b * SS * DD;
    if (t < 256) {
        const int s    = t >> 6;
        const int lane = t & 63;
        const int kr   = lane & 31, h = lane >> 5;
        const float* src = Vb + (size_t)(slot * 32 + kr) * DD + s * 16 + h * 8;
        f32x4 a = *(const f32x4*)src;
        f32x4 c = *(const f32x4*)(src + 4);
        half8_t hi, lo;
#pragma unroll
        for (int j = 0; j < 4; ++j) {
            float x = a[j]; h16 hh = (h16)x;
            hi[j] = hh; lo[j] = (h16)(x - (float)hh);        // exact residual
            float y = c[j]; h16 gg = (h16)y;
            hi[j + 4] = gg; lo[j + 4] = (h16)(y - (float)gg);
        }
        *(half8_t*)(img + s * 2048 + lane * 16) = hi;
        *(half8_t*)(img + s * 2048 + 1024 + lane * 16) = lo;
    } else {
        const int u    = t - 256;
        const int ks   = u >> 7;
        const int o    = (u >> 6) & 1;
        const int lane = u & 63;
        const int kr   = lane & 31, h = lane >> 5;
        const int d    = o * 32 + kr;
        half8_t v;
#pragma unroll
        for (int j = 0; j < 8; ++j)
            v[j] = (h16)Vb[(size_t)(slot * 32 + ks * 16 + h * 8 + j) * DD + d];
        *(half8_t*)(img + 8192 + ks * 2048 + o * 1024 + lane * 16) = v;
    }
}

// S^T = V*Q^T for one 32-key slot x 32 queries; f16x2-split, 12 MFMA. All loads
// are coalesced 1KB global (L2-resident image) -- no LDS, no barriers.
__device__ __forceinline__ f32x16 scores12(const char* sb, const half8_t* qh,
                                           const half8_t* ql, int lane) {
    f32x16 sa = Z16, sc = Z16;
#pragma unroll
    for (int s = 0; s < 4; ++s) {
        half8_t ah = *(const half8_t*)(sb + s * 2048 + lane * 16);
        half8_t al = *(const half8_t*)(sb + s * 2048 + 1024 + lane * 16);
        if (s & 1) {
            sc = __builtin_amdgcn_mfma_f32_32x32x16_f16(ah, qh[s], sc, 0, 0, 0);
            sc = __builtin_amdgcn_mfma_f32_32x32x16_f16(ah, ql[s], sc, 0, 0, 0);
            sc = __builtin_amdgcn_mfma_f32_32x32x16_f16(al, qh[s], sc, 0, 0, 0);
        } else {
            sa = __builtin_amdgcn_mfma_f32_32x32x16_f16(ah, qh[s], sa, 0, 0, 0);
            sa = __builtin_amdgcn_mfma_f32_32x32x16_f16(ah, ql[s], sa, 0, 0, 0);
            sa = __builtin_amdgcn_mfma_f32_32x32x16_f16(al, qh[s], sa, 0, 0, 0);
        }
    }
    return sa + sc;
}

__device__ __forceinline__ void load_q(const float* Qrow, half8_t* qh, half8_t* ql) {
#pragma unroll
    for (int s = 0; s < 4; ++s) {
        f32x4 a = *(const f32x4*)(Qrow + s * 16);        // h folded below
        (void)a;
    }
}

// Q frags f16x2: lane(kr,h) holds Q[q=kr][d = s*16 + h*8 + j]
__device__ __forceinline__ void qfrags(const float* Qrow, int h, half8_t* qh, half8_t* ql) {
#pragma unroll
    for (int s = 0; s < 4; ++s) {
        f32x4 a = *(const f32x4*)(Qrow + s * 16 + h * 8);
        f32x4 c = *(const f32x4*)(Qrow + s * 16 + h * 8 + 4);
#pragma unroll
        for (int j = 0; j < 4; ++j) {
            float x = a[j]; h16 hh = (h16)x;
            qh[s][j] = hh; ql[s][j] = (h16)(x - (float)hh);
            float y = c[j]; h16 gg = (h16)y;
            qh[s][j + 4] = gg; ql[s][j + 4] = (h16)(y - (float)gg);
        }
    }
}

// ------------ pass 1: per-row (m,l) partials; no LDS, no barriers ------------
__global__ __launch_bounds__(512, 4) void stats_pass(const float* __restrict__ Q,
                                                     const char* __restrict__ W,
                                                     f32x2* __restrict__ ml) {
    const int t    = threadIdx.x;
    const int wid  = t >> 6;
    const int lane = t & 63;
    const int kr   = lane & 31, h = lane >> 5;
    const int bid  = blockIdx.x;                 // 256
    const int b    = bid & 3;                    // XCD-pinned batch
    const int u    = (bid >> 2) * 8 + wid;       // 0..511 jobs per batch
    const int qgb  = u >> 2;                     // 0..127 qgroup in batch
    const int kspl = u & 3;
    const char* img = W + (size_t)b * IMGB;
    const float* Qrow = Q + ((size_t)b * SS + qgb * 32 + kr) * DD;

    half8_t qh[4], ql[4];
    qfrags(Qrow, h, qh, ql);

    float mrun = -1e30f, lrun = 0.f;
#pragma unroll 2
    for (int slot = kspl * 32; slot < kspl * 32 + 32; ++slot) {
        f32x16 sc = scores12(img + (size_t)slot * SLOTB, qh, ql, lane);
        float tmax = sc[0];
#pragma unroll
        for (int i = 1; i < 16; ++i) tmax = fmaxf(tmax, sc[i]);
        tmax = fmaxf(tmax, __shfl_xor(tmax, 32));
        const float mn = fmaxf(mrun, tmax);
        float ps = 0.f;
#pragma unroll
        for (int i = 0; i < 16; ++i) ps += __expf(sc[i] - mn);
        ps += __shfl_xor(ps, 32);
        const bool still  = __all(tmax <= mrun);
        const float alpha = still ? 1.f : __expf(mrun - mn);
        lrun = lrun * alpha + ps;
        mrun = mn;
    }
    if (h == 0)
        ml[((size_t)b * SS + qgb * 32 + kr) * KS + kspl] = (f32x2){mrun, lrun};
}

// ------------ pass 2: weights + ctx. k-parallel waves, one barrier total ------------
__global__ __launch_bounds__(512, 4) void attn_pass(const float* __restrict__ Q,
                                                    const char* __restrict__ W,
                                                    const f32x2* __restrict__ ml,
                                                    float* __restrict__ ctx,
                                                    float* __restrict__ attn) {
    __shared__ float red[8][32][66];             // 67584 B, bank-padded
    const int t    = threadIdx.x;
    const int wid  = t >> 6;
    const int lane = t & 63;
    const int kr   = lane & 31, h = lane >> 5;
    const int bid  = blockIdx.x;                 // 512
    const int b    = bid & 3;                    // XCD-pinned batch
    const int qgb  = bid >> 2;                   // 0..127
    const size_t row = (size_t)b * SS + qgb * 32 + kr;
    const char* img = W + (size_t)b * IMGB;

    // finalize softmax stats inline: moff = m + log l  ->  weight = exp(s - moff)
    f32x2 s0 = ml[row * KS + 0], s1 = ml[row * KS + 1];
    f32x2 s2 = ml[row * KS + 2], s3 = ml[row * KS + 3];
    float mg = fmaxf(fmaxf(s0[0], s1[0]), fmaxf(s2[0], s3[0]));
    float lg = s0[1] * __expf(s0[0] - mg) + s1[1] * __expf(s1[0] - mg) +
               s2[1] * __expf(s2[0] - mg) + s3[1] * __expf(s3[0] - mg);
    const float moff = mg + __logf(lg);

    half8_t qh[4], ql[4];
    qfrags(Q + row * DD, h, qh, ql);

    f32x16 oc0 = Z16, oc1 = Z16;
    float* arow = attn + row * SS;

#pragma unroll 1
    for (int i = 0; i < 16; ++i) {
        const int slot = wid * 16 + i;           // disjoint k-range per wave
        const char* sb = img + (size_t)slot * SLOTB;
        f32x16 sc = scores12(sb, qh, ql, lane);
        float p[16];
#pragma unroll
        for (int j = 0; j < 16; ++j) p[j] = __expf(sc[j] - moff);
        // weights: normal stores; L2 recombines the 16B/row chunks (exact in r0/r2)
#pragma unroll
        for (int g = 0; g < 4; ++g) {
            f32x4 wv = {p[g * 4], p[g * 4 + 1], p[g * 4 + 2], p[g * 4 + 3]};
            *(f32x4*)&arow[slot * 32 + g * 8 + h * 4] = wv;
        }
        // P -> f16 B-frags in-register
        unsigned w0 = pkh(p[0], p[1]),   w1 = pkh(p[2], p[3]);
        unsigned w2 = pkh(p[4], p[5]),   w3 = pkh(p[6], p[7]);
        unsigned w4 = pkh(p[8], p[9]),   w5 = pkh(p[10], p[11]);
        unsigned w6 = pkh(p[12], p[13]), w7 = pkh(p[14], p[15]);
        xpair(w0, w2, h); xpair(w1, w3, h); xpair(w4, w6, h); xpair(w5, w7, h);
        half8_t pb0 = __builtin_bit_cast(half8_t, (u32x4v){w0, w1, w2, w3});
        half8_t pb1 = __builtin_bit_cast(half8_t, (u32x4v){w4, w5, w6, w7});
        // O^T += V^T * P^T (weights are final: no rescale, no cross-iter dependency)
#pragma unroll
        for (int ks = 0; ks < 2; ++ks) {
            const half8_t bp = ks ? pb1 : pb0;
            half8_t av0 = *(const half8_t*)(sb + 8192 + ks * 2048 + lane * 16);
            half8_t av1 = *(const half8_t*)(sb + 8192 + ks * 2048 + 1024 + lane * 16);
            oc0 = __builtin_amdgcn_mfma_f32_32x32x16_f16(av0, bp, oc0, 0, 0, 0);
            oc1 = __builtin_amdgcn_mfma_f32_32x32x16_f16(av1, bp, oc1, 0, 0, 0);
        }
    }

    // ctx: per-wave partials -> LDS (padded, conflict-free) -> tree sum -> coalesced write
#pragma unroll
    for (int g = 0; g < 4; ++g) {
        f32x4 a = {oc0[g * 4], oc0[g * 4 + 1], oc0[g * 4 + 2], oc0[g * 4 + 3]};
        f32x4 c = {oc1[g * 4], oc1[g * 4 + 1], oc1[g * 4 + 2], oc1[g * 4 + 3]};
        *(f32x4*)&red[wid][kr][g * 8 + h * 4]      = a;   // d = g*8+h*4+m
        *(f32x4*)&red[wid][kr][32 + g * 8 + h * 4] = c;   // d+32
    }
    __syncthreads();
    const int q = t >> 4, c16 = t & 15;
    f32x4 sum = {0.f, 0.f, 0.f, 0.f};
#pragma unroll
    for (int w2 = 0; w2 < 8; ++w2) sum += *(const f32x4*)&red[w2][q][c16 * 4];
    *(f32x4*)&ctx[((size_t)b * SS + qgb * 32 + q) * DD + c16 * 4] = sum;
}

extern "C" void kernel_launch(void* const* d_in, const int* in_sizes, int n_in,
                              void* d_out, int out_size, void* d_ws, size_t ws_size,
                              hipStream_t stream) {
    const float* Q = (const float*)d_in[0];
    const float* V = (const float*)d_in[1];
    float* ctx  = (float*)d_out;
    float* attn = (float*)d_out + (size_t)BB * SS * DD;
    char*  W  = (char*)d_ws;                              // 6.29 MiB image
    f32x2* ml = (f32x2*)(W + BB * IMGB);                  // +0.50 MiB partials
    prep_v<<<dim3(NSLOT, BB), 512, 0, stream>>>(V, W);
    stats_pass<<<dim3(256), 512, 0, stream>>>(Q, W, ml);
    attn_pass<<<dim3(512), 512, 0, stream>>>(Q, W, ml, ctx, attn);
}

// Round 5
// 353.693 us; speedup vs baseline: 1.2699x; 1.0536x over previous
//
#include <hip/hip_runtime.h>

#define BB 4
#define SS 4096
#define DD 64
#define NSLOT 128                       // 32-key slots per batch
#define SLOTB 12288                     // slot image: SCO 8K + PV 4K
#define IMGB ((size_t)NSLOT * SLOTB)    // 1.5 MiB per batch
#define KS 4                            // k-splits in the stats pass

typedef _Float16 h16;
typedef h16 half2_t __attribute__((ext_vector_type(2)));
typedef h16 half8_t __attribute__((ext_vector_type(8)));
typedef float f32x2 __attribute__((ext_vector_type(2)));
typedef float f32x4 __attribute__((ext_vector_type(4)));
typedef float f32x16 __attribute__((ext_vector_type(16)));
typedef unsigned u32x4v __attribute__((ext_vector_type(4)));

#define Z16 ((f32x16){0.f,0.f,0.f,0.f,0.f,0.f,0.f,0.f,0.f,0.f,0.f,0.f,0.f,0.f,0.f,0.f})

__device__ __forceinline__ unsigned pkh(float a, float b) {
    half2_t x = {(h16)a, (h16)b};
    return __builtin_bit_cast(unsigned, x);
}

__device__ __forceinline__ void xpair(unsigned& wl, unsigned& wh, int h) {
    unsigned xl = (unsigned)__shfl_xor((int)wl, 32);
    unsigned xh = (unsigned)__shfl_xor((int)wh, 32);
    unsigned nl = h ? xh : wl;
    unsigned nh = h ? wh : xl;
    wl = nl; wh = nh;
}

// ------------ prep: V -> fragment-major f16x2-split image (per 32-key slot) ------------
__global__ __launch_bounds__(512) void prep_v(const float* __restrict__ V,
                                              char* __restrict__ W) {
    const int t    = threadIdx.x;
    const int slot = blockIdx.x;
    const int b    = blockIdx.y;
    char* img = W + (size_t)b * IMGB + (size_t)slot * SLOTB;
    const float* Vb = V + (size_t)b * SS * DD;
    if (t < 256) {
        const int s    = t >> 6;
        const int lane = t & 63;
        const int kr   = lane & 31, h = lane >> 5;
        const float* src = Vb + (size_t)(slot * 32 + kr) * DD + s * 16 + h * 8;
        f32x4 a = *(const f32x4*)src;
        f32x4 c = *(const f32x4*)(src + 4);
        half8_t hi, lo;
#pragma unroll
        for (int j = 0; j < 4; ++j) {
            float x = a[j]; h16 hh = (h16)x;
            hi[j] = hh; lo[j] = (h16)(x - (float)hh);        // exact residual
            float y = c[j]; h16 gg = (h16)y;
            hi[j + 4] = gg; lo[j + 4] = (h16)(y - (float)gg);
        }
        *(half8_t*)(img + s * 2048 + lane * 16) = hi;
        *(half8_t*)(img + s * 2048 + 1024 + lane * 16) = lo;
    } else {
        const int u    = t - 256;
        const int ks   = u >> 7;
        const int o    = (u >> 6) & 1;
        const int lane = u & 63;
        const int kr   = lane & 31, h = lane >> 5;
        const int d    = o * 32 + kr;
        half8_t v;
#pragma unroll
        for (int j = 0; j < 8; ++j)
            v[j] = (h16)Vb[(size_t)(slot * 32 + ks * 16 + h * 8 + j) * DD + d];
        *(half8_t*)(img + 8192 + ks * 2048 + o * 1024 + lane * 16) = v;
    }
}

// Q frags f16x2: lane(kr,h) holds Q[q=kr][d = s*16 + h*8 + j]
__device__ __forceinline__ void qfrags(const float* Qrow, int h, half8_t* qh, half8_t* ql) {
#pragma unroll
    for (int s = 0; s < 4; ++s) {
        f32x4 a = *(const f32x4*)(Qrow + s * 16 + h * 8);
        f32x4 c = *(const f32x4*)(Qrow + s * 16 + h * 8 + 4);
#pragma unroll
        for (int j = 0; j < 4; ++j) {
            float x = a[j]; h16 hh = (h16)x;
            qh[s][j] = hh; ql[s][j] = (h16)(x - (float)hh);
            float y = c[j]; h16 gg = (h16)y;
            qh[s][j + 4] = gg; ql[s][j + 4] = (h16)(y - (float)gg);
        }
    }
}

// online (m,l) update from one 16-reg score tile (identical math to round 4)
__device__ __forceinline__ void ml_update(const f32x16& sc, float& mrun, float& lrun) {
    float tmax = sc[0];
#pragma unroll
    for (int i = 1; i < 16; ++i) tmax = fmaxf(tmax, sc[i]);
    tmax = fmaxf(tmax, __shfl_xor(tmax, 32));
    const float mn = fmaxf(mrun, tmax);
    float ps = 0.f;
#pragma unroll
    for (int i = 0; i < 16; ++i) ps += __expf(sc[i] - mn);
    ps += __shfl_xor(ps, 32);
    const bool still  = __all(tmax <= mrun);
    const float alpha = still ? 1.f : __expf(mrun - mn);
    lrun = lrun * alpha + ps;
    mrun = mn;
}

// S^T = V*Q^T for one 32-key slot x 32 queries; f16x2-split, 12 MFMA.
__device__ __forceinline__ f32x16 scores12(const char* sb, const half8_t* qh,
                                           const half8_t* ql, int lane) {
    f32x16 sa = Z16, sc = Z16;
#pragma unroll
    for (int s = 0; s < 4; ++s) {
        half8_t ah = *(const half8_t*)(sb + s * 2048 + lane * 16);
        half8_t al = *(const half8_t*)(sb + s * 2048 + 1024 + lane * 16);
        if (s & 1) {
            sc = __builtin_amdgcn_mfma_f32_32x32x16_f16(ah, qh[s], sc, 0, 0, 0);
            sc = __builtin_amdgcn_mfma_f32_32x32x16_f16(ah, ql[s], sc, 0, 0, 0);
            sc = __builtin_amdgcn_mfma_f32_32x32x16_f16(al, qh[s], sc, 0, 0, 0);
        } else {
            sa = __builtin_amdgcn_mfma_f32_32x32x16_f16(ah, qh[s], sa, 0, 0, 0);
            sa = __builtin_amdgcn_mfma_f32_32x32x16_f16(ah, ql[s], sa, 0, 0, 0);
            sa = __builtin_amdgcn_mfma_f32_32x32x16_f16(al, qh[s], sa, 0, 0, 0);
        }
    }
    return sa + sc;
}

// ------------ pass 1: per-row (m,l) partials; q-pair per wave shares V loads ------------
__global__ __launch_bounds__(256, 4) void stats_pass(const float* __restrict__ Q,
                                                     const char* __restrict__ W,
                                                     f32x2* __restrict__ ml) {
    const int t    = threadIdx.x;
    const int wid  = t >> 6;                     // 0..3
    const int lane = t & 63;
    const int kr   = lane & 31, h = lane >> 5;
    const int bid  = blockIdx.x;                 // 256
    const int b    = bid & 3;                    // XCD-pinned batch
    const int job  = (bid >> 2) * 4 + wid;       // 0..255 per batch
    const int qp   = job >> 2;                   // 0..63: q-pair (64 rows)
    const int kspl = job & 3;
    const char* img = W + (size_t)b * IMGB;
    const size_t q0row = (size_t)b * SS + qp * 64 + kr;
    const size_t q1row = q0row + 32;

    half8_t qh0[4], ql0[4], qh1[4], ql1[4];
    qfrags(Q + q0row * DD, h, qh0, ql0);
    qfrags(Q + q1row * DD, h, qh1, ql1);

    float m0 = -1e30f, l0 = 0.f, m1 = -1e30f, l1 = 0.f;
#pragma unroll 1
    for (int slot = kspl * 32; slot < kspl * 32 + 32; ++slot) {
        const char* sb = img + (size_t)slot * SLOTB;
        f32x16 s0 = Z16, s1 = Z16;
#pragma unroll
        for (int s = 0; s < 4; ++s) {
            half8_t ah = *(const half8_t*)(sb + s * 2048 + lane * 16);
            half8_t al = *(const half8_t*)(sb + s * 2048 + 1024 + lane * 16);
            s0 = __builtin_amdgcn_mfma_f32_32x32x16_f16(ah, qh0[s], s0, 0, 0, 0);
            s1 = __builtin_amdgcn_mfma_f32_32x32x16_f16(ah, qh1[s], s1, 0, 0, 0);
            s0 = __builtin_amdgcn_mfma_f32_32x32x16_f16(ah, ql0[s], s0, 0, 0, 0);
            s1 = __builtin_amdgcn_mfma_f32_32x32x16_f16(ah, ql1[s], s1, 0, 0, 0);
            s0 = __builtin_amdgcn_mfma_f32_32x32x16_f16(al, qh0[s], s0, 0, 0, 0);
            s1 = __builtin_amdgcn_mfma_f32_32x32x16_f16(al, qh1[s], s1, 0, 0, 0);
        }
        ml_update(s0, m0, l0);
        ml_update(s1, m1, l1);
    }
    if (h == 0) {
        ml[q0row * KS + kspl] = (f32x2){m0, l0};
        ml[q1row * KS + kspl] = (f32x2){m1, l1};
    }
}

// ------------ pass 2: weights + ctx; LDS-transposed coalesced weight stores ------------
__global__ __launch_bounds__(512, 4) void attn_pass(const float* __restrict__ Q,
                                                    const char* __restrict__ W,
                                                    const f32x2* __restrict__ ml,
                                                    float* __restrict__ ctx,
                                                    float* __restrict__ attn) {
    __shared__ float LB[16896];                  // 67584 B: tiles [8][1024] / red [8][32][66]
    const int t    = threadIdx.x;
    const int wid  = t >> 6;
    const int lane = t & 63;
    const int kr   = lane & 31, h = lane >> 5;
    const int bid  = blockIdx.x;                 // 512
    const int b    = bid & 3;                    // XCD-pinned batch
    const int qgb  = bid >> 2;                   // 0..127
    const size_t row = (size_t)b * SS + qgb * 32 + kr;
    const char* img = W + (size_t)b * IMGB;
    float* tile = LB + wid * 1024;               // per-wave 32x32 f32 transpose tile

    // finalize softmax stats: moff = m + log l  ->  weight = exp(s - moff)
    f32x2 s0 = ml[row * KS + 0], s1 = ml[row * KS + 1];
    f32x2 s2 = ml[row * KS + 2], s3 = ml[row * KS + 3];
    float mg = fmaxf(fmaxf(s0[0], s1[0]), fmaxf(s2[0], s3[0]));
    float lg = s0[1] * __expf(s0[0] - mg) + s1[1] * __expf(s1[0] - mg) +
               s2[1] * __expf(s2[0] - mg) + s3[1] * __expf(s3[0] - mg);
    const float moff = mg + __logf(lg);

    half8_t qh[4], ql[4];
    qfrags(Q + row * DD, h, qh, ql);

    f32x16 oc0 = Z16, oc1 = Z16;
    float* aBase = attn + ((size_t)b * SS + qgb * 32) * SS;   // row-major [32 rows][SS]

#pragma unroll 1
    for (int i = 0; i < 16; ++i) {
        const int slot = wid * 16 + i;           // disjoint k-range per wave
        const char* sb = img + (size_t)slot * SLOTB;
        f32x16 sc = scores12(sb, qh, ql, lane);
        float p[16];
#pragma unroll
        for (int j = 0; j < 16; ++j) p[j] = __expf(sc[j] - moff);

        // ---- weight store, transposed through per-wave LDS tile (T2 XOR swizzle) ----
        // write: lane(kr,h) holds keys k = 8g+4h+m for q-row kr; chunk = k>>2 = 2g+h
#pragma unroll
        for (int g = 0; g < 4; ++g) {
            f32x4 wv = {p[g * 4], p[g * 4 + 1], p[g * 4 + 2], p[g * 4 + 3]};
            const int chunk = (2 * g + h) ^ (kr & 7);
            *(f32x4*)&tile[kr * 32 + chunk * 4] = wv;
        }
        // same-wave in-order DS pipe: reads below see the writes above (no barrier)
#pragma unroll
        for (int j = 0; j < 4; ++j) {
            const int rrow = j * 8 + (lane >> 3);
            const int cc   = lane & 7;
            f32x4 v = *(const f32x4*)&tile[rrow * 32 + ((cc ^ (rrow & 7)) * 4)];
            // lanes 0..7 -> one row, consecutive 16B: 8 x 128B segments per instr
            *(f32x4*)&aBase[(size_t)rrow * SS + slot * 32 + cc * 4] = v;
        }

        // ---- P -> f16 B-frags in-register, then PV accumulate ----
        unsigned w0 = pkh(p[0], p[1]),   w1 = pkh(p[2], p[3]);
        unsigned w2 = pkh(p[4], p[5]),   w3 = pkh(p[6], p[7]);
        unsigned w4 = pkh(p[8], p[9]),   w5 = pkh(p[10], p[11]);
        unsigned w6 = pkh(p[12], p[13]), w7 = pkh(p[14], p[15]);
        xpair(w0, w2, h); xpair(w1, w3, h); xpair(w4, w6, h); xpair(w5, w7, h);
        half8_t pb0 = __builtin_bit_cast(half8_t, (u32x4v){w0, w1, w2, w3});
        half8_t pb1 = __builtin_bit_cast(half8_t, (u32x4v){w4, w5, w6, w7});
#pragma unroll
        for (int ks = 0; ks < 2; ++ks) {
            const half8_t bp = ks ? pb1 : pb0;
            half8_t av0 = *(const half8_t*)(sb + 8192 + ks * 2048 + lane * 16);
            half8_t av1 = *(const half8_t*)(sb + 8192 + ks * 2048 + 1024 + lane * 16);
            oc0 = __builtin_amdgcn_mfma_f32_32x32x16_f16(av0, bp, oc0, 0, 0, 0);
            oc1 = __builtin_amdgcn_mfma_f32_32x32x16_f16(av1, bp, oc1, 0, 0, 0);
        }
    }

    // ctx: per-wave partials -> LDS -> tree sum -> coalesced write
    __syncthreads();                             // tiles done (LB region reused below)
    float (*red)[32][66] = (float(*)[32][66])LB;
#pragma unroll
    for (int g = 0; g < 4; ++g) {
        f32x4 a = {oc0[g * 4], oc0[g * 4 + 1], oc0[g * 4 + 2], oc0[g * 4 + 3]};
        f32x4 c = {oc1[g * 4], oc1[g * 4 + 1], oc1[g * 4 + 2], oc1[g * 4 + 3]};
        *(f32x4*)&red[wid][kr][g * 8 + h * 4]      = a;   // d = g*8+h*4+m
        *(f32x4*)&red[wid][kr][32 + g * 8 + h * 4] = c;   // d+32
    }
    __syncthreads();
    const int q = t >> 4, c16 = t & 15;
    f32x4 sum = {0.f, 0.f, 0.f, 0.f};
#pragma unroll
    for (int w2 = 0; w2 < 8; ++w2) sum += *(const f32x4*)&red[w2][q][c16 * 4];
    *(f32x4*)&ctx[((size_t)b * SS + qgb * 32 + q) * DD + c16 * 4] = sum;
}

extern "C" void kernel_launch(void* const* d_in, const int* in_sizes, int n_in,
                              void* d_out, int out_size, void* d_ws, size_t ws_size,
                              hipStream_t stream) {
    const float* Q = (const float*)d_in[0];
    const float* V = (const float*)d_in[1];
    float* ctx  = (float*)d_out;
    float* attn = (float*)d_out + (size_t)BB * SS * DD;
    char*  W  = (char*)d_ws;                              // 6.29 MiB image
    f32x2* ml = (f32x2*)(W + BB * IMGB);                  // +0.50 MiB partials
    prep_v<<<dim3(NSLOT, BB), 512, 0, stream>>>(V, W);
    stats_pass<<<dim3(256), 256, 0, stream>>>(Q, W, ml);
    attn_pass<<<dim3(512), 512, 0, stream>>>(Q, W, ml, ctx, attn);
}